// Round 4
// baseline (102.971 us; speedup 1.0000x reference)
//
#include <hip/hip_runtime.h>

#define NBINS 101
#define NB2 (2 * NBINS)    // 202 bins total (pos + neg)
#define NTHREADS 256
#define NCOPY 16           // histogram replicas, one per lane&15 (13 KB LDS)
#define CNT_SHIFT 22
#define QMAX 413695u       // (100<<12) | 4095 : clamps idx to <= 100
#define GSHIFT 38          // global u64 packing: (count << 38) | frac_q12
#define NREP 64            // global accumulator replicas (burst de-contention)
#define FSCALE 452.5483399593904f   // sqrt(50 * 4096): folds (s+1)*204800 into MFMA

typedef _Float16 half8 __attribute__((ext_vector_type(8)));
typedef float floatx4 __attribute__((ext_vector_type(4)));

// ---------------------------------------------------------------------------
// R13: de-contend + occupancy.
// R12 post-mortem: books say hist ~30us (was ~23 in R11). Only change was the
// epilogue: 420k u64 atomics into 8 replica rows -> ~130-deep same-address
// bursts (block completions cluster) x ~150cyc serialized = ~8-10us tail.
// Fix 1: NREP 8->64 (blockIdx&63; adjacent blocks hit distinct replicas).
// Fix 2: hist core is latency-bound (VALUBusy ~5%, floor ~9us): NCOPY 32->16
//        (LDS 25.9->12.9KB) + launch_bounds(256,8) -> 8 blocks/CU, 100% wave
//        occupancy (was 5 blocks). Packed LDS fields still carry-safe at
//        <=64 adds/word. VGPR already exactly 64 -> fits 8 waves/SIMD.
// Fix 3: finalize now sums 64 rows (103KB) -> 1024 threads, u64 partials
//        (carry-free), fp64 tail unchanged.
// ---------------------------------------------------------------------------

__global__ __launch_bounds__(NTHREADS)
void convert_kernel(const float* __restrict__ feats,
                    const int* __restrict__ classes,
                    _Float16* __restrict__ wsF,
                    unsigned char* __restrict__ wsC,
                    unsigned long long* __restrict__ gH,  // [NREP][NB2]
                    int ngroups,   // N*D/8 groups of 8 floats
                    int n) {       // N (classes)
    int t = blockIdx.x * NTHREADS + threadIdx.x;
    if (t < ngroups) {
        const float4* p = (const float4*)feats + (size_t)t * 2;
        float4 f0 = p[0];
        float4 f1 = p[1];
        half8 h;
        h[0] = (_Float16)(f0.x * FSCALE); h[1] = (_Float16)(f0.y * FSCALE);
        h[2] = (_Float16)(f0.z * FSCALE); h[3] = (_Float16)(f0.w * FSCALE);
        h[4] = (_Float16)(f1.x * FSCALE); h[5] = (_Float16)(f1.y * FSCALE);
        h[6] = (_Float16)(f1.z * FSCALE); h[7] = (_Float16)(f1.w * FSCALE);
        *(half8*)(wsF + (size_t)t * 8) = h;
    }
    if (t < n) wsC[t] = (unsigned char)classes[t];
    // zero global accumulators (workspace is poisoned each iteration);
    // stream order guarantees completion before hist_pairs launches.
    if (blockIdx.x == 0) {
        for (int z = threadIdx.x; z < NREP * NB2; z += NTHREADS) gH[z] = 0ull;
    }
}

// ---------------------------------------------------------------------------
// One 64x64 upper-triangular tile per BLOCK; wave w computes the 16x64 strip
// rows [w*16, w*16+16). half8 fragment loads from the scaled f16 workspace;
// acc arrives in q-space (bias pre-added); one ds_add_u32 per pair;
// per-block unpack -> one u64 global atomicAdd per bin (64-way replica).
// ---------------------------------------------------------------------------
__global__ __launch_bounds__(NTHREADS, 8)
void hist_pairs_kernel(const _Float16* __restrict__ feats16,
                       const unsigned char* __restrict__ cls8,
                       unsigned long long* __restrict__ gH,  // [NREP][NB2]
                       int ntiles) {
    __shared__ unsigned lhist[NB2][NCOPY];   // packed count|frac, 12.9 KB
    __shared__ __align__(16) int cls[2][64]; // [A/B][row], shared by all waves

    const int tid = threadIdx.x;
    const int wave = tid >> 6;
    const int lane = tid & 63;

    // zero local histograms (uint4 stores: 808 x 16B / 256 thr)
    {
        uint4* z = (uint4*)&lhist[0][0];
        uint4 zero = {0u, 0u, 0u, 0u};
        for (int t = tid; t < NB2 * NCOPY / 4; t += NTHREADS) z[t] = zero;
    }

    // decode block -> upper-triangular tile (ti, tj)
    int ti = 0, tj = 0;
    {
        int rem = blockIdx.x;
        while (rem >= ntiles - ti) { rem -= ntiles - ti; ++ti; }
        tj = ti + rem;
    }
    if (tid < 64)        cls[0][tid]      = cls8[ti * 64 + tid];
    else if (tid < 128)  cls[1][tid - 64] = cls8[tj * 64 + (tid - 64)];
    __syncthreads();

    {
        const int i0 = ti * 64, j0 = tj * 64;
        const int lr = lane & 15;
        const int quad = lane >> 4;

        // wave-private A strip (16 rows), block-shared B tile (64 cols)
        const _Float16* Ab = feats16 + (size_t)(i0 + wave * 16 + lr) * 128 + quad * 8;
        const _Float16* Bb = feats16 + (size_t)(j0 + lr) * 128 + quad * 8;

        // acc initialized to the binning bias: (s+1)*204800 + 0.5 rounding
        floatx4 acc[4];
        #pragma unroll
        for (int ni = 0; ni < 4; ++ni) {
            acc[ni][0] = 204800.5f; acc[ni][1] = 204800.5f;
            acc[ni][2] = 204800.5f; acc[ni][3] = 204800.5f;
        }

        #pragma unroll
        for (int ks = 0; ks < 128; ks += 32) {
            half8 af = *(const half8*)(Ab + ks);
            half8 bf[4];
            #pragma unroll
            for (int ni = 0; ni < 4; ++ni)
                bf[ni] = *(const half8*)(Bb + (size_t)ni * 16 * 128 + ks);
            #pragma unroll
            for (int ni = 0; ni < 4; ++ni)
                acc[ni] = __builtin_amdgcn_mfma_f32_16x16x32_f16(
                    af, bf[ni], acc[ni], 0, 0, 0);
        }

        // classes for this lane's C fragment rows/cols
        int cA[4], cB[4];
        {
            int4 c4 = *(const int4*)&cls[0][wave * 16 + quad * 4];
            cA[0] = c4.x; cA[1] = c4.y; cA[2] = c4.z; cA[3] = c4.w;
        }
        #pragma unroll
        for (int ni = 0; ni < 4; ++ni) cB[ni] = cls[1][ni * 16 + lr];

        // binning: acc already equals q + tiny fp noise. One ds_add_u32/pair.
        const int copy = lane & (NCOPY - 1);
        unsigned* hb = &lhist[0][0] + copy;
        const bool diag = (ti == tj);
        #pragma unroll
        for (int ni = 0; ni < 4; ++ni) {
            #pragma unroll
            for (int r = 0; r < 4; ++r) {
                const int li = wave * 16 + quad * 4 + r;
                const int lj = ni * 16 + lr;
                if (diag && li >= lj) continue;  // strict upper triangle
                float qf = fmaxf(acc[ni][r], 0.0f);
                unsigned q = (unsigned)qf;
                q = q > QMAX ? QMAX : q;
                unsigned idx = q >> 12;
                unsigned word = (q & 4095u) | (1u << CNT_SHIFT);
                unsigned hoff = (cA[r] == cB[ni]) ? 0u : (unsigned)NBINS;
                atomicAdd(hb + (hoff + idx) * NCOPY, word);
            }
        }
    }
    __syncthreads();

    // per-bin unpack: C = sum(w>>22), Fq = sum(w&mask) (q12 fixed point).
    // Max adds per (bin,copy) = 4 lanes * 16 pairs = 64 -> fields safe
    // (cnt <= 64 < 2^10, frac <= 64*4095 < 2^22).
    // Pack (C<<38)|Fq into one u64 atomicAdd; global C-sum = 8.39e6 < 2^26,
    // global F-sum <= 3.44e10 < 2^38: carry-free across all 2080 blocks.
    const int t = tid;
    if (t < NB2) {
        unsigned Cs = 0, Fq = 0;
        #pragma unroll
        for (int c = 0; c < NCOPY; ++c) {
            unsigned w = lhist[t][(c + t) & (NCOPY - 1)];
            Cs += w >> CNT_SHIFT;
            Fq += w & ((1u << CNT_SHIFT) - 1);
        }
        unsigned long long word =
            ((unsigned long long)Cs << GSHIFT) | (unsigned long long)Fq;
        atomicAdd(&gH[(blockIdx.x & (NREP - 1)) * NB2 + t], word);
    }
}

// ---------------------------------------------------------------------------
// Finalize: sum 64 replica rows (103KB, 1024 thr, u64 carry-free partials),
// unpack, telescope, fp64 cumsum.
// ---------------------------------------------------------------------------
__global__ __launch_bounds__(1024)
void finalize_kernel(const unsigned long long* __restrict__ gH,
                     float* __restrict__ out) {
    __shared__ unsigned long long accS[5][NB2];
    __shared__ double hd[NB2];
    const int t = threadIdx.x;
    const int g = t / NB2;          // row-group 0..4 (t >= 1010 idle)
    const int bin = t - g * NB2;
    if (g < 5) {
        unsigned long long s = 0ull;
        #pragma unroll 4
        for (int r = g; r < NREP; r += 5)
            s += gH[r * NB2 + bin];
        accS[g][bin] = s;
    }
    __syncthreads();
    if (t < NB2) {
        unsigned long long w = accS[0][t] + accS[1][t] + accS[2][t]
                             + accS[3][t] + accS[4][t];
        double C = (double)(w >> GSHIFT);
        double F = (double)(w & ((1ull << GSHIFT) - 1)) * (1.0 / 4096.0);
        hd[t] = C;   // temporarily store C; telescope needs F[t-1] too
        accS[0][t] = w;  // keep packed word for neighbor access
    }
    __syncthreads();
    if (t < NB2) {
        unsigned long long w = accS[0][t];
        double C = (double)(w >> GSHIFT);
        double F = (double)(w & ((1ull << GSHIFT) - 1)) * (1.0 / 4096.0);
        double Fp = 0.0;
        if (t > 0) {
            unsigned long long wp = accS[0][t - 1];
            Fp = (double)(wp & ((1ull << GSHIFT) - 1)) * (1.0 / 4096.0);
        }
        const int lo = (t < NBINS) ? 0 : NBINS;
        const int hi = lo + NBINS - 1;
        double h = C;
        if (t < hi) h -= F;
        if (t > lo) h += Fp;
        hd[t] = h;
    }
    __syncthreads();
    if (t == 0) {
        double sp = 0.0, sn = 0.0;
        for (int k = 0; k < NBINS; ++k) { sp += hd[k]; sn += hd[NBINS + k]; }
        double isp = 1.0 / sp, isn = 1.0 / sn;
        double cdf = 0.0, res = 0.0;
        for (int k = 0; k < NBINS; ++k) {
            cdf += hd[k] * isp;                   // inclusive cumsum of pos
            res += hd[NBINS + k] * isn * cdf;     // dot with neg
        }
        out[0] = (float)res;
    }
}

extern "C" void kernel_launch(void* const* d_in, const int* in_sizes, int n_in,
                              void* d_out, int out_size, void* d_ws, size_t ws_size,
                              hipStream_t stream) {
    const float* feats   = (const float*)d_in[0];
    const int*   classes = (const int*)d_in[1];
    float* out = (float*)d_out;

    int N = in_sizes[1];                       // 4096
    int D = in_sizes[0] / N;                   // 128
    int ntiles = N / 64;                       // 64
    int nblocks = ntiles * (ntiles + 1) / 2;   // 2080 blocks, one tile each

    // workspace layout: f16 scaled feats | u8 classes | u64 gH[NREP][NB2]
    _Float16* wsF = (_Float16*)d_ws;
    unsigned char* wsC = (unsigned char*)(wsF + (size_t)N * D);
    unsigned long long* gH = (unsigned long long*)(wsC + ((N + 15) & ~15));

    int ngroups = N * D / 8;                   // 65536 groups of 8 floats
    int cblocks = (ngroups + NTHREADS - 1) / NTHREADS;
    convert_kernel<<<cblocks, NTHREADS, 0, stream>>>(feats, classes, wsF, wsC,
                                                     gH, ngroups, N);
    hist_pairs_kernel<<<nblocks, NTHREADS, 0, stream>>>(wsF, wsC, gH, ntiles);
    finalize_kernel<<<1, 1024, 0, stream>>>(gH, out);
}

// Round 5
// 84.625 us; speedup vs baseline: 1.2168x; 1.2168x over previous
//
#include <hip/hip_runtime.h>

#define NBINS 101
#define NB2 (2 * NBINS)    // 202 bins total (pos + neg)
#define NTHREADS 256
#define NCOPY 32           // histogram replicas, one per lane&31 (bank = copy)
#define CNT_SHIFT 22
#define QMAX 413695u       // (100<<12) | 4095 : clamps idx to <= 100
#define GSHIFT 38          // global u64 packing: (count << 38) | frac_q12
#define NREP 32            // global accumulator replicas (burst de-contention)
#define FSCALE 452.5483399593904f   // sqrt(50 * 4096): folds (s+1)*204800 into MFMA

typedef _Float16 half8 __attribute__((ext_vector_type(8)));
typedef float floatx4 __attribute__((ext_vector_type(4)));

// ---------------------------------------------------------------------------
// R14: surgical revert. R13 bundled 3 changes and regressed 84.2->103.0; its
// profile shows finalize_kernel with a 75us dispatch span at ~zero activity,
// and NCOPY=16 provably adds 4-way LDS-atomic aliasing (1.58x, m136). Revert
// to byte-level R12 (NCOPY=32, launch_bounds(256,4), small 256-thr finalize)
// with ONE change: NREP 8->32. That targets R12's identified defect (420k
// u64 atomics into 8 rows -> ~130-deep same-address serialized bursts);
// 32 replicas cuts burst depth 4x, finalize still tiny (52KB, 32 unrolled
// loads/thread). Integer atomics remain order-independent -> deterministic.
// ---------------------------------------------------------------------------

__global__ __launch_bounds__(NTHREADS)
void convert_kernel(const float* __restrict__ feats,
                    const int* __restrict__ classes,
                    _Float16* __restrict__ wsF,
                    unsigned char* __restrict__ wsC,
                    unsigned long long* __restrict__ gH,  // [NREP][NB2]
                    int ngroups,   // N*D/8 groups of 8 floats
                    int n) {       // N (classes)
    int t = blockIdx.x * NTHREADS + threadIdx.x;
    if (t < ngroups) {
        const float4* p = (const float4*)feats + (size_t)t * 2;
        float4 f0 = p[0];
        float4 f1 = p[1];
        half8 h;
        h[0] = (_Float16)(f0.x * FSCALE); h[1] = (_Float16)(f0.y * FSCALE);
        h[2] = (_Float16)(f0.z * FSCALE); h[3] = (_Float16)(f0.w * FSCALE);
        h[4] = (_Float16)(f1.x * FSCALE); h[5] = (_Float16)(f1.y * FSCALE);
        h[6] = (_Float16)(f1.z * FSCALE); h[7] = (_Float16)(f1.w * FSCALE);
        *(half8*)(wsF + (size_t)t * 8) = h;
    }
    if (t < n) wsC[t] = (unsigned char)classes[t];
    // zero global accumulators (workspace is poisoned each iteration);
    // stream order guarantees completion before hist_pairs launches.
    if (blockIdx.x == 0) {
        for (int z = threadIdx.x; z < NREP * NB2; z += NTHREADS) gH[z] = 0ull;
    }
}

// ---------------------------------------------------------------------------
// One 64x64 upper-triangular tile per BLOCK; wave w computes the 16x64 strip
// rows [w*16, w*16+16). half8 fragment loads from the scaled f16 workspace;
// acc arrives in q-space (bias pre-added); one ds_add_u32 per pair;
// per-block unpack -> one u64 global atomicAdd per bin (32-way replica).
// ---------------------------------------------------------------------------
__global__ __launch_bounds__(NTHREADS, 4)
void hist_pairs_kernel(const _Float16* __restrict__ feats16,
                       const unsigned char* __restrict__ cls8,
                       unsigned long long* __restrict__ gH,  // [NREP][NB2]
                       int ntiles) {
    __shared__ unsigned lhist[NB2][NCOPY];   // packed count|frac, 25.9 KB
    __shared__ __align__(16) int cls[2][64]; // [A/B][row], shared by all waves

    const int tid = threadIdx.x;
    const int wave = tid >> 6;
    const int lane = tid & 63;

    // zero local histograms (uint4 stores: 1616 x 16B / 256 thr)
    {
        uint4* z = (uint4*)&lhist[0][0];
        uint4 zero = {0u, 0u, 0u, 0u};
        for (int t = tid; t < NB2 * NCOPY / 4; t += NTHREADS) z[t] = zero;
    }

    // decode block -> upper-triangular tile (ti, tj)
    int ti = 0, tj = 0;
    {
        int rem = blockIdx.x;
        while (rem >= ntiles - ti) { rem -= ntiles - ti; ++ti; }
        tj = ti + rem;
    }
    if (tid < 64)        cls[0][tid]      = cls8[ti * 64 + tid];
    else if (tid < 128)  cls[1][tid - 64] = cls8[tj * 64 + (tid - 64)];
    __syncthreads();

    {
        const int i0 = ti * 64, j0 = tj * 64;
        const int lr = lane & 15;
        const int quad = lane >> 4;

        // wave-private A strip (16 rows), block-shared B tile (64 cols)
        const _Float16* Ab = feats16 + (size_t)(i0 + wave * 16 + lr) * 128 + quad * 8;
        const _Float16* Bb = feats16 + (size_t)(j0 + lr) * 128 + quad * 8;

        // acc initialized to the binning bias: (s+1)*204800 + 0.5 rounding
        floatx4 acc[4];
        #pragma unroll
        for (int ni = 0; ni < 4; ++ni) {
            acc[ni][0] = 204800.5f; acc[ni][1] = 204800.5f;
            acc[ni][2] = 204800.5f; acc[ni][3] = 204800.5f;
        }

        #pragma unroll
        for (int ks = 0; ks < 128; ks += 32) {
            half8 af = *(const half8*)(Ab + ks);
            half8 bf[4];
            #pragma unroll
            for (int ni = 0; ni < 4; ++ni)
                bf[ni] = *(const half8*)(Bb + (size_t)ni * 16 * 128 + ks);
            #pragma unroll
            for (int ni = 0; ni < 4; ++ni)
                acc[ni] = __builtin_amdgcn_mfma_f32_16x16x32_f16(
                    af, bf[ni], acc[ni], 0, 0, 0);
        }

        // classes for this lane's C fragment rows/cols
        int cA[4], cB[4];
        {
            int4 c4 = *(const int4*)&cls[0][wave * 16 + quad * 4];
            cA[0] = c4.x; cA[1] = c4.y; cA[2] = c4.z; cA[3] = c4.w;
        }
        #pragma unroll
        for (int ni = 0; ni < 4; ++ni) cB[ni] = cls[1][ni * 16 + lr];

        // binning: acc already equals q + tiny fp noise. One ds_add_u32/pair.
        const int copy = lane & (NCOPY - 1);
        unsigned* hb = &lhist[0][0] + copy;
        const bool diag = (ti == tj);
        #pragma unroll
        for (int ni = 0; ni < 4; ++ni) {
            #pragma unroll
            for (int r = 0; r < 4; ++r) {
                const int li = wave * 16 + quad * 4 + r;
                const int lj = ni * 16 + lr;
                if (diag && li >= lj) continue;  // strict upper triangle
                float qf = fmaxf(acc[ni][r], 0.0f);
                unsigned q = (unsigned)qf;
                q = q > QMAX ? QMAX : q;
                unsigned idx = q >> 12;
                unsigned word = (q & 4095u) | (1u << CNT_SHIFT);
                unsigned hoff = (cA[r] == cB[ni]) ? 0u : (unsigned)NBINS;
                atomicAdd(hb + (hoff + idx) * NCOPY, word);
            }
        }
    }
    __syncthreads();

    // per-bin unpack: C = sum(w>>22), Fq = sum(w&mask) (q12 fixed point).
    // Max adds per (bin,copy) = 2 lanes * 16 pairs = 32 -> fields safe
    // (cnt <= 32 < 2^10, frac <= 32*4095 < 2^17 < 2^22).
    // Pack (C<<38)|Fq into one u64 atomicAdd; global C-sum = 8.39e6 < 2^26,
    // global F-sum <= 3.44e10 < 2^38: carry-free across all 2080 blocks.
    const int t = tid;
    if (t < NB2) {
        unsigned Cs = 0, Fq = 0;
        #pragma unroll
        for (int c = 0; c < NCOPY; ++c) {
            unsigned w = lhist[t][(c + t) & (NCOPY - 1)];
            Cs += w >> CNT_SHIFT;
            Fq += w & ((1u << CNT_SHIFT) - 1);
        }
        unsigned long long word =
            ((unsigned long long)Cs << GSHIFT) | (unsigned long long)Fq;
        atomicAdd(&gH[(blockIdx.x & (NREP - 1)) * NB2 + t], word);
    }
}

// ---------------------------------------------------------------------------
// Tiny finalize: sum 32 replica rows (52KB, unrolled independent loads),
// unpack, telescope, fp64 cumsum.
// ---------------------------------------------------------------------------
__global__ __launch_bounds__(NTHREADS)
void finalize_kernel(const unsigned long long* __restrict__ gH,
                     float* __restrict__ out) {
    __shared__ double Cd[NB2];
    __shared__ double Fd[NB2];
    __shared__ double hd[NB2];
    const int t = threadIdx.x;
    if (t < NB2) {
        unsigned long long w = 0ull;
        #pragma unroll
        for (int r = 0; r < NREP; ++r) w += gH[r * NB2 + t];
        Cd[t] = (double)(w >> GSHIFT);
        Fd[t] = (double)(w & ((1ull << GSHIFT) - 1)) * (1.0 / 4096.0);
    }
    __syncthreads();
    if (t < NB2) {
        const int lo = (t < NBINS) ? 0 : NBINS;
        const int hi = lo + NBINS - 1;
        double h = Cd[t];
        if (t < hi) h -= Fd[t];
        if (t > lo) h += Fd[t - 1];
        hd[t] = h;
    }
    __syncthreads();
    if (t == 0) {
        double sp = 0.0, sn = 0.0;
        for (int k = 0; k < NBINS; ++k) { sp += hd[k]; sn += hd[NBINS + k]; }
        double isp = 1.0 / sp, isn = 1.0 / sn;
        double cdf = 0.0, res = 0.0;
        for (int k = 0; k < NBINS; ++k) {
            cdf += hd[k] * isp;                   // inclusive cumsum of pos
            res += hd[NBINS + k] * isn * cdf;     // dot with neg
        }
        out[0] = (float)res;
    }
}

extern "C" void kernel_launch(void* const* d_in, const int* in_sizes, int n_in,
                              void* d_out, int out_size, void* d_ws, size_t ws_size,
                              hipStream_t stream) {
    const float* feats   = (const float*)d_in[0];
    const int*   classes = (const int*)d_in[1];
    float* out = (float*)d_out;

    int N = in_sizes[1];                       // 4096
    int D = in_sizes[0] / N;                   // 128
    int ntiles = N / 64;                       // 64
    int nblocks = ntiles * (ntiles + 1) / 2;   // 2080 blocks, one tile each

    // workspace layout: f16 scaled feats | u8 classes | u64 gH[NREP][NB2]
    _Float16* wsF = (_Float16*)d_ws;
    unsigned char* wsC = (unsigned char*)(wsF + (size_t)N * D);
    unsigned long long* gH = (unsigned long long*)(wsC + ((N + 15) & ~15));

    int ngroups = N * D / 8;                   // 65536 groups of 8 floats
    int cblocks = (ngroups + NTHREADS - 1) / NTHREADS;
    convert_kernel<<<cblocks, NTHREADS, 0, stream>>>(feats, classes, wsF, wsC,
                                                     gH, ngroups, N);
    hist_pairs_kernel<<<nblocks, NTHREADS, 0, stream>>>(wsF, wsC, gH, ntiles);
    finalize_kernel<<<1, NTHREADS, 0, stream>>>(gH, out);
}

// Round 6
// 83.506 us; speedup vs baseline: 1.2331x; 1.0134x over previous
//
#include <hip/hip_runtime.h>

#define NBINS 101
#define NB2 (2 * NBINS)    // 202 bins total (pos + neg)
#define NTHREADS 256
#define NCOPY 32           // histogram replicas, one per lane&31 (bank = copy)
#define CNT_SHIFT 22
#define QMAX 413695u       // (100<<12) | 4095 : clamps idx to <= 100
#define GSHIFT 38          // global u64 packing: (count << 38) | frac_q12
#define NREP 32            // global accumulator replicas
#define FSCALE 452.5483399593904f   // sqrt(50 * 4096): folds (s+1)*204800 into MFMA

typedef _Float16 half8 __attribute__((ext_vector_type(8)));
typedef float floatx4 __attribute__((ext_vector_type(4)));

// ---------------------------------------------------------------------------
// R15: tile-size round (single conceptual change from the R14 anchor).
// R14 post-mortem: NREP 8->32 was a no-op (84.2->84.6) -> atomic-burst theory
// dead. Budget says hist ~28-32us vs ~9us floor; its 2080 tiny blocks re-issue
// the B-tile per wave (166MB L2 traffic), re-zero 25.9KB LDS, re-unpack, 2080x.
// Change: 64x64 -> 128x128 tile per block. 528 blocks; wave w = 32x128 strip
// (acc[2][8] = 64 VGPR, ~120 total under the 128 cap). Load traffic halves
// (84.5MB), epilogue/zero/atomic overheads drop 4x. Packing bounds re-proven:
// per-(bin,copy) <=128 adds (cnt<2^10, frac<2^22); per-block Cs<=16384<2^26,
// Fq<=6.7e7<2^38; global C 8.39e6<2^26, F 3.44e10<2^38. Everything else
// byte-identical to R14.
// ---------------------------------------------------------------------------

__global__ __launch_bounds__(NTHREADS)
void convert_kernel(const float* __restrict__ feats,
                    const int* __restrict__ classes,
                    _Float16* __restrict__ wsF,
                    unsigned char* __restrict__ wsC,
                    unsigned long long* __restrict__ gH,  // [NREP][NB2]
                    int ngroups,   // N*D/8 groups of 8 floats
                    int n) {       // N (classes)
    int t = blockIdx.x * NTHREADS + threadIdx.x;
    if (t < ngroups) {
        const float4* p = (const float4*)feats + (size_t)t * 2;
        float4 f0 = p[0];
        float4 f1 = p[1];
        half8 h;
        h[0] = (_Float16)(f0.x * FSCALE); h[1] = (_Float16)(f0.y * FSCALE);
        h[2] = (_Float16)(f0.z * FSCALE); h[3] = (_Float16)(f0.w * FSCALE);
        h[4] = (_Float16)(f1.x * FSCALE); h[5] = (_Float16)(f1.y * FSCALE);
        h[6] = (_Float16)(f1.z * FSCALE); h[7] = (_Float16)(f1.w * FSCALE);
        *(half8*)(wsF + (size_t)t * 8) = h;
    }
    if (t < n) wsC[t] = (unsigned char)classes[t];
    // zero global accumulators (workspace is poisoned each iteration);
    // stream order guarantees completion before hist_pairs launches.
    if (blockIdx.x == 0) {
        for (int z = threadIdx.x; z < NREP * NB2; z += NTHREADS) gH[z] = 0ull;
    }
}

// ---------------------------------------------------------------------------
// One 128x128 upper-triangular tile per BLOCK; wave w computes the 32x128
// strip rows [w*32, w*32+32). half8 fragment loads from the scaled f16
// workspace; acc arrives in q-space (bias pre-added); one ds_add_u32 per
// pair; per-block unpack -> one u64 global atomicAdd per bin.
// ---------------------------------------------------------------------------
__global__ __launch_bounds__(NTHREADS, 4)
void hist_pairs_kernel(const _Float16* __restrict__ feats16,
                       const unsigned char* __restrict__ cls8,
                       unsigned long long* __restrict__ gH,  // [NREP][NB2]
                       int ntiles) {
    __shared__ unsigned lhist[NB2][NCOPY];    // packed count|frac, 25.9 KB
    __shared__ __align__(16) int cls[2][128]; // [A/B][row], shared by all waves

    const int tid = threadIdx.x;
    const int wave = tid >> 6;
    const int lane = tid & 63;

    // zero local histograms (uint4 stores: 1616 x 16B / 256 thr)
    {
        uint4* z = (uint4*)&lhist[0][0];
        uint4 zero = {0u, 0u, 0u, 0u};
        for (int t = tid; t < NB2 * NCOPY / 4; t += NTHREADS) z[t] = zero;
    }

    // decode block -> upper-triangular tile (ti, tj), ntiles = 32
    int ti = 0, tj = 0;
    {
        int rem = blockIdx.x;
        while (rem >= ntiles - ti) { rem -= ntiles - ti; ++ti; }
        tj = ti + rem;
    }
    if (tid < 128)  cls[0][tid]       = cls8[ti * 128 + tid];
    else            cls[1][tid - 128] = cls8[tj * 128 + (tid - 128)];
    __syncthreads();

    {
        const int i0 = ti * 128, j0 = tj * 128;
        const int lr = lane & 15;
        const int quad = lane >> 4;

        // wave-private A strip (32 rows), block-shared B tile (128 cols)
        const _Float16* Ab = feats16 + (size_t)(i0 + wave * 32 + lr) * 128 + quad * 8;
        const _Float16* Bb = feats16 + (size_t)(j0 + lr) * 128 + quad * 8;

        // acc initialized to the binning bias: (s+1)*204800 + 0.5 rounding
        floatx4 acc[2][8];
        #pragma unroll
        for (int mi = 0; mi < 2; ++mi)
            #pragma unroll
            for (int ni = 0; ni < 8; ++ni) {
                acc[mi][ni][0] = 204800.5f; acc[mi][ni][1] = 204800.5f;
                acc[mi][ni][2] = 204800.5f; acc[mi][ni][3] = 204800.5f;
            }

        #pragma unroll
        for (int ks = 0; ks < 128; ks += 32) {
            half8 af[2];
            #pragma unroll
            for (int mi = 0; mi < 2; ++mi)
                af[mi] = *(const half8*)(Ab + (size_t)mi * 16 * 128 + ks);
            half8 bf[8];
            #pragma unroll
            for (int ni = 0; ni < 8; ++ni)
                bf[ni] = *(const half8*)(Bb + (size_t)ni * 16 * 128 + ks);
            #pragma unroll
            for (int mi = 0; mi < 2; ++mi)
                #pragma unroll
                for (int ni = 0; ni < 8; ++ni)
                    acc[mi][ni] = __builtin_amdgcn_mfma_f32_16x16x32_f16(
                        af[mi], bf[ni], acc[mi][ni], 0, 0, 0);
        }

        // classes for this lane's C fragment rows/cols
        int cA[2][4], cB[8];
        #pragma unroll
        for (int mi = 0; mi < 2; ++mi) {
            int4 c4 = *(const int4*)&cls[0][wave * 32 + mi * 16 + quad * 4];
            cA[mi][0] = c4.x; cA[mi][1] = c4.y;
            cA[mi][2] = c4.z; cA[mi][3] = c4.w;
        }
        #pragma unroll
        for (int ni = 0; ni < 8; ++ni) cB[ni] = cls[1][ni * 16 + lr];

        // binning: acc already equals q + tiny fp noise. One ds_add_u32/pair.
        const int copy = lane & (NCOPY - 1);
        unsigned* hb = &lhist[0][0] + copy;
        const bool diag = (ti == tj);
        #pragma unroll
        for (int mi = 0; mi < 2; ++mi) {
            #pragma unroll
            for (int ni = 0; ni < 8; ++ni) {
                #pragma unroll
                for (int r = 0; r < 4; ++r) {
                    const int li = wave * 32 + mi * 16 + quad * 4 + r;
                    const int lj = ni * 16 + lr;
                    if (diag && li >= lj) continue;  // strict upper triangle
                    float qf = fmaxf(acc[mi][ni][r], 0.0f);
                    unsigned q = (unsigned)qf;
                    q = q > QMAX ? QMAX : q;
                    unsigned idx = q >> 12;
                    unsigned word = (q & 4095u) | (1u << CNT_SHIFT);
                    unsigned hoff = (cA[mi][r] == cB[ni]) ? 0u : (unsigned)NBINS;
                    atomicAdd(hb + (hoff + idx) * NCOPY, word);
                }
            }
        }
    }
    __syncthreads();

    // per-bin unpack: C = sum(w>>22), Fq = sum(w&mask) (q12 fixed point).
    // Max adds per (bin,copy) = 2 lanes * 64 pairs = 128 -> fields safe
    // (cnt <= 128 < 2^10, frac <= 128*4095 < 2^22).
    // Pack (C<<38)|Fq into one u64 atomicAdd; per-block Cs <= 16384 < 2^26,
    // Fq <= 6.7e7 < 2^38; global C-sum 8.39e6 < 2^26, F-sum 3.44e10 < 2^38:
    // carry-free across all 528 blocks.
    const int t = tid;
    if (t < NB2) {
        unsigned Cs = 0, Fq = 0;
        #pragma unroll
        for (int c = 0; c < NCOPY; ++c) {
            unsigned w = lhist[t][(c + t) & (NCOPY - 1)];
            Cs += w >> CNT_SHIFT;
            Fq += w & ((1u << CNT_SHIFT) - 1);
        }
        unsigned long long word =
            ((unsigned long long)Cs << GSHIFT) | (unsigned long long)Fq;
        atomicAdd(&gH[(blockIdx.x & (NREP - 1)) * NB2 + t], word);
    }
}

// ---------------------------------------------------------------------------
// Tiny finalize: sum 32 replica rows (52KB, unrolled independent loads),
// unpack, telescope, fp64 cumsum.
// ---------------------------------------------------------------------------
__global__ __launch_bounds__(NTHREADS)
void finalize_kernel(const unsigned long long* __restrict__ gH,
                     float* __restrict__ out) {
    __shared__ double Cd[NB2];
    __shared__ double Fd[NB2];
    __shared__ double hd[NB2];
    const int t = threadIdx.x;
    if (t < NB2) {
        unsigned long long w = 0ull;
        #pragma unroll
        for (int r = 0; r < NREP; ++r) w += gH[r * NB2 + t];
        Cd[t] = (double)(w >> GSHIFT);
        Fd[t] = (double)(w & ((1ull << GSHIFT) - 1)) * (1.0 / 4096.0);
    }
    __syncthreads();
    if (t < NB2) {
        const int lo = (t < NBINS) ? 0 : NBINS;
        const int hi = lo + NBINS - 1;
        double h = Cd[t];
        if (t < hi) h -= Fd[t];
        if (t > lo) h += Fd[t - 1];
        hd[t] = h;
    }
    __syncthreads();
    if (t == 0) {
        double sp = 0.0, sn = 0.0;
        for (int k = 0; k < NBINS; ++k) { sp += hd[k]; sn += hd[NBINS + k]; }
        double isp = 1.0 / sp, isn = 1.0 / sn;
        double cdf = 0.0, res = 0.0;
        for (int k = 0; k < NBINS; ++k) {
            cdf += hd[k] * isp;                   // inclusive cumsum of pos
            res += hd[NBINS + k] * isn * cdf;     // dot with neg
        }
        out[0] = (float)res;
    }
}

extern "C" void kernel_launch(void* const* d_in, const int* in_sizes, int n_in,
                              void* d_out, int out_size, void* d_ws, size_t ws_size,
                              hipStream_t stream) {
    const float* feats   = (const float*)d_in[0];
    const int*   classes = (const int*)d_in[1];
    float* out = (float*)d_out;

    int N = in_sizes[1];                       // 4096
    int D = in_sizes[0] / N;                   // 128
    int ntiles = N / 128;                      // 32
    int nblocks = ntiles * (ntiles + 1) / 2;   // 528 blocks, one tile each

    // workspace layout: f16 scaled feats | u8 classes | u64 gH[NREP][NB2]
    _Float16* wsF = (_Float16*)d_ws;
    unsigned char* wsC = (unsigned char*)(wsF + (size_t)N * D);
    unsigned long long* gH = (unsigned long long*)(wsC + ((N + 15) & ~15));

    int ngroups = N * D / 8;                   // 65536 groups of 8 floats
    int cblocks = (ngroups + NTHREADS - 1) / NTHREADS;
    convert_kernel<<<cblocks, NTHREADS, 0, stream>>>(feats, classes, wsF, wsC,
                                                     gH, ngroups, N);
    hist_pairs_kernel<<<nblocks, NTHREADS, 0, stream>>>(wsF, wsC, gH, ntiles);
    finalize_kernel<<<1, NTHREADS, 0, stream>>>(gH, out);
}